// Round 1
// baseline (1695.526 us; speedup 1.0000x reference)
//
#include <hip/hip_runtime.h>

// NSVF render, fused: per-point MLP + per-ray volumetric rendering.
// Layout: one wave (64 lanes) per ray; lane = sample index.
// All weight accesses are wave-uniform -> scalar (s_load) weight fetches.

#define NRAYS 8192
#define MAXS  64
#define EMB   32
#define HID   128
#define NPE   27   // 3 + 6*L_VIEW, L_VIEW=4
#define CH    64

__device__ __forceinline__ float wave_sum(float v) {
#pragma unroll
  for (int off = 32; off > 0; off >>= 1) v += __shfl_down(v, off, 64);
  return v;  // lane 0 holds the total
}

__device__ __forceinline__ float wave_prefix_excl(float v, int lane) {
  float inc = v;
#pragma unroll
  for (int off = 1; off < 64; off <<= 1) {
    float u = __shfl_up(inc, off, 64);
    if (lane >= off) inc += u;
  }
  return inc - v;
}

// out[j] = act( B[j] + sum_k in[k] * W[k*J + j] ), j=0..J-1
// Weights indexed wave-uniformly; in/out are per-thread scratch arrays.
template <int K, int J, bool RELU>
__device__ void dense_layer(const float* __restrict__ W, const float* __restrict__ B,
                            const float* __restrict__ in, float* __restrict__ out) {
  const float4* in4 = (const float4*)in;
#pragma unroll 1
  for (int jc = 0; jc < J; jc += 8) {
    float acc[8];
#pragma unroll
    for (int u = 0; u < 8; ++u) acc[u] = B[jc + u];
#pragma unroll 4
    for (int k4 = 0; k4 < K / 4; ++k4) {
      const float4 x = in4[k4];
      const float* Wr = W + (k4 * 4) * J + jc;
#pragma unroll
      for (int u = 0; u < 8; ++u) acc[u] = fmaf(x.x, Wr[u], acc[u]);
#pragma unroll
      for (int u = 0; u < 8; ++u) acc[u] = fmaf(x.y, Wr[J + u], acc[u]);
#pragma unroll
      for (int u = 0; u < 8; ++u) acc[u] = fmaf(x.z, Wr[2 * J + u], acc[u]);
#pragma unroll
      for (int u = 0; u < 8; ++u) acc[u] = fmaf(x.w, Wr[3 * J + u], acc[u]);
    }
    if (RELU) {
#pragma unroll
      for (int u = 0; u < 8; ++u) acc[u] = fmaxf(acc[u], 0.f);
    }
    ((float4*)out)[jc / 4]     = make_float4(acc[0], acc[1], acc[2], acc[3]);
    ((float4*)out)[jc / 4 + 1] = make_float4(acc[4], acc[5], acc[6], acc[7]);
  }
}

__global__ __launch_bounds__(256) void nsvf_render_kernel(
    const float* __restrict__ rays_d, const float* __restrict__ pts,
    const float* __restrict__ t_vals, const float* __restrict__ dists,
    const int* __restrict__ p2v, const float* __restrict__ vox_emb,
    const float* __restrict__ Wpts,
    const float* __restrict__ W1, const float* __restrict__ b1,
    const float* __restrict__ W2, const float* __restrict__ b2,
    const float* __restrict__ Wsig, const float* __restrict__ bsig,
    const float* __restrict__ Wfeat, const float* __restrict__ bfeat,
    const float* __restrict__ Wc1, const float* __restrict__ bc1,
    const float* __restrict__ Wc2, const float* __restrict__ bc2,
    float* __restrict__ out_rgb, float* __restrict__ out_disp,
    float* __restrict__ out_acc) {
  const int lane = threadIdx.x & 63;
  const int ray  = blockIdx.x * 4 + (threadIdx.x >> 6);
  const int pidx = ray * MAXS + lane;

  const int vidx = p2v[pidx];
  // counts >= 1, so sample 0 is valid iff ray_hits: derive hit from p2v row 0.
  const bool hit = (__shfl(vidx, 0, 64) >= 0);
  if (!hit) {
    if (lane < 3) out_rgb[ray * 3 + lane] = 0.f;
    if (lane == 0) { out_disp[ray] = 0.f; out_acc[ray] = 0.f; }
    return;
  }
  const bool valid = vidx >= 0;
  const int  gidx  = valid ? vidx : 0;

  // ---- voxel embedding + positional lift: ve = vox_emb[gidx] + pts @ Wpts
  alignas(16) float ve[EMB];
  {
    const float px = pts[pidx * 3 + 0];
    const float py = pts[pidx * 3 + 1];
    const float pz = pts[pidx * 3 + 2];
    const float4* vrow = (const float4*)vox_emb + gidx * (EMB / 4);
    const float4* wp   = (const float4*)Wpts;
#pragma unroll
    for (int e4 = 0; e4 < EMB / 4; ++e4) {
      float4 v  = vrow[e4];
      float4 w0 = wp[e4];
      float4 w1 = wp[EMB / 4 + e4];
      float4 w2 = wp[2 * (EMB / 4) + e4];
      float4 r;
      r.x = v.x + fmaf(px, w0.x, fmaf(py, w1.x, pz * w2.x));
      r.y = v.y + fmaf(px, w0.y, fmaf(py, w1.y, pz * w2.y));
      r.z = v.z + fmaf(px, w0.z, fmaf(py, w1.z, pz * w2.z));
      r.w = v.w + fmaf(px, w0.w, fmaf(py, w1.w, pz * w2.w));
      ((float4*)ve)[e4] = r;
    }
  }

  // ---- MLP trunk
  alignas(16) float h1[HID];
  alignas(16) float h2[HID];
  alignas(16) float feat[HID];
  dense_layer<EMB, HID, true>(W1, b1, ve, h1);
  dense_layer<HID, HID, true>(W2, b2, h1, h2);

  // sigma = h2 @ Wsig + bsig
  float sigma;
  {
    float sa0 = 0.f, sa1 = 0.f, sa2 = 0.f, sa3 = 0.f;
    const float4* h24 = (const float4*)h2;
    const float4* ws4 = (const float4*)Wsig;
#pragma unroll 4
    for (int k4 = 0; k4 < HID / 4; ++k4) {
      float4 x = h24[k4];
      float4 w = ws4[k4];
      sa0 = fmaf(x.x, w.x, sa0);
      sa1 = fmaf(x.y, w.y, sa1);
      sa2 = fmaf(x.z, w.z, sa2);
      sa3 = fmaf(x.w, w.w, sa3);
    }
    sigma = bsig[0] + ((sa0 + sa1) + (sa2 + sa3));
  }

  dense_layer<HID, HID, false>(Wfeat, bfeat, h2, feat);

  // ---- view positional encoding (wave-uniform values, computed per lane)
  float vemb[NPE];
  {
    const float d0 = rays_d[ray * 3 + 0];
    const float d1 = rays_d[ray * 3 + 1];
    const float d2 = rays_d[ray * 3 + 2];
    vemb[0] = d0; vemb[1] = d1; vemb[2] = d2;
#pragma unroll
    for (int i = 0; i < 3; ++i) {
      const float di = (i == 0) ? d0 : (i == 1) ? d1 : d2;
#pragma unroll
      for (int l = 0; l < 4; ++l) {
        const float ang = di * (float)(1 << l);
        vemb[3 + i * 4 + l]      = __sinf(ang);
        vemb[3 + 12 + i * 4 + l] = __cosf(ang);
      }
    }
  }

  // ---- color head layer 1: c = relu([feat, vemb] @ Wc1 + bc1)
  alignas(16) float cc[CH];
  {
    const float4* in4 = (const float4*)feat;
#pragma unroll 1
    for (int jc = 0; jc < CH; jc += 8) {
      float acc[8];
#pragma unroll
      for (int u = 0; u < 8; ++u) acc[u] = bc1[jc + u];
#pragma unroll 4
      for (int k4 = 0; k4 < HID / 4; ++k4) {
        const float4 x = in4[k4];
        const float* Wr = Wc1 + (k4 * 4) * CH + jc;
#pragma unroll
        for (int u = 0; u < 8; ++u) acc[u] = fmaf(x.x, Wr[u], acc[u]);
#pragma unroll
        for (int u = 0; u < 8; ++u) acc[u] = fmaf(x.y, Wr[CH + u], acc[u]);
#pragma unroll
        for (int u = 0; u < 8; ++u) acc[u] = fmaf(x.z, Wr[2 * CH + u], acc[u]);
#pragma unroll
        for (int u = 0; u < 8; ++u) acc[u] = fmaf(x.w, Wr[3 * CH + u], acc[u]);
      }
#pragma unroll
      for (int v = 0; v < NPE; ++v) {
        const float* Wr = Wc1 + (HID + v) * CH + jc;
#pragma unroll
        for (int u = 0; u < 8; ++u) acc[u] = fmaf(vemb[v], Wr[u], acc[u]);
      }
#pragma unroll
      for (int u = 0; u < 8; ++u) acc[u] = fmaxf(acc[u], 0.f);
      ((float4*)cc)[jc / 4]     = make_float4(acc[0], acc[1], acc[2], acc[3]);
      ((float4*)cc)[jc / 4 + 1] = make_float4(acc[4], acc[5], acc[6], acc[7]);
    }
  }

  // ---- color head layer 2: rgb_raw = cc @ Wc2 + bc2
  float r0 = bc2[0], r1 = bc2[1], r2 = bc2[2];
  {
    const float4* c4 = (const float4*)cc;
#pragma unroll 4
    for (int k4 = 0; k4 < CH / 4; ++k4) {
      float4 x = c4[k4];
      const float* Wr = Wc2 + (k4 * 4) * 3;
      r0 = fmaf(x.x, Wr[0], r0); r1 = fmaf(x.x, Wr[1], r1); r2 = fmaf(x.x, Wr[2], r2);
      r0 = fmaf(x.y, Wr[3], r0); r1 = fmaf(x.y, Wr[4], r1); r2 = fmaf(x.y, Wr[5], r2);
      r0 = fmaf(x.z, Wr[6], r0); r1 = fmaf(x.z, Wr[7], r1); r2 = fmaf(x.z, Wr[8], r2);
      r0 = fmaf(x.w, Wr[9], r0); r1 = fmaf(x.w, Wr[10], r1); r2 = fmaf(x.w, Wr[11], r2);
    }
  }

  // ---- volumetric rendering across the wave (lane = sample)
  const float fe   = valid ? fmaxf(sigma, 0.f) * dists[pidx] : 0.f;
  const float pref = wave_prefix_excl(fe, lane);           // cumsum(shifted)
  const float T    = __expf(-pref);
  const float w    = (1.f - __expf(-fe)) * T;              // exactly 0 for invalid lanes
  const float tv   = t_vals[pidx];

  // rgb remap (+1)*0.5; invalid lanes have w==0 so their value is irrelevant
  const float crgb0 = wave_sum(w * (r0 + 1.f) * 0.5f);
  const float crgb1 = wave_sum(w * (r1 + 1.f) * 0.5f);
  const float crgb2 = wave_sum(w * (r2 + 1.f) * 0.5f);
  const float accs  = wave_sum(w);
  const float depth = wave_sum(w * tv);

  if (lane == 0) {
    out_rgb[ray * 3 + 0] = crgb0;
    out_rgb[ray * 3 + 1] = crgb1;
    out_rgb[ray * 3 + 2] = crgb2;
    const float disp = 1.f / fmaxf(1e-10f, depth / fmaxf(accs, 1e-10f));
    out_disp[ray] = disp;
    out_acc[ray]  = accs;
  }
}

extern "C" void kernel_launch(void* const* d_in, const int* in_sizes, int n_in,
                              void* d_out, int out_size, void* d_ws, size_t ws_size,
                              hipStream_t stream) {
  // setup_inputs() dict order:
  // 0 rays_d, 1 pts, 2 t_vals, 3 dists, 4 p2v_idx, 5 ray_hits(bool, unused),
  // 6 vox_emb, 7 Wpts, 8 W1, 9 b1, 10 W2, 11 b2, 12 Wsig, 13 bsig,
  // 14 Wfeat, 15 bfeat, 16 Wc1, 17 bc1, 18 Wc2, 19 bc2
  const float* rays_d  = (const float*)d_in[0];
  const float* pts     = (const float*)d_in[1];
  const float* t_vals  = (const float*)d_in[2];
  const float* dists   = (const float*)d_in[3];
  const int*   p2v     = (const int*)d_in[4];
  const float* vox_emb = (const float*)d_in[6];
  const float* Wpts    = (const float*)d_in[7];
  const float* W1      = (const float*)d_in[8];
  const float* b1      = (const float*)d_in[9];
  const float* W2      = (const float*)d_in[10];
  const float* b2      = (const float*)d_in[11];
  const float* Wsig    = (const float*)d_in[12];
  const float* bsig    = (const float*)d_in[13];
  const float* Wfeat   = (const float*)d_in[14];
  const float* bfeat   = (const float*)d_in[15];
  const float* Wc1     = (const float*)d_in[16];
  const float* bc1     = (const float*)d_in[17];
  const float* Wc2     = (const float*)d_in[18];
  const float* bc2     = (const float*)d_in[19];

  float* out      = (float*)d_out;
  float* out_rgb  = out;                 // [8192,3]
  float* out_disp = out + NRAYS * 3;     // [8192]
  float* out_acc  = out + NRAYS * 4;     // [8192]

  dim3 grid(NRAYS / 4), block(256);      // 4 rays (waves) per block
  hipLaunchKernelGGL(nsvf_render_kernel, grid, block, 0, stream,
                     rays_d, pts, t_vals, dists, p2v, vox_emb, Wpts,
                     W1, b1, W2, b2, Wsig, bsig, Wfeat, bfeat,
                     Wc1, bc1, Wc2, bc2, out_rgb, out_disp, out_acc);
}